// Round 1
// 16450.940 us; speedup vs baseline: 1.5641x; 1.5641x over previous
//
#include <hip/hip_runtime.h>

#define NB 64
#define NT 512
#define NIN 1024
#define NH 1024
#define NWG 128

typedef _Float16 half8 __attribute__((ext_vector_type(8)));
typedef _Float16 half4 __attribute__((ext_vector_type(4)));
typedef float floatx4 __attribute__((ext_vector_type(4)));

union HV8 { _Float16 h[8]; uint4 u; };
union HV4 { _Float16 h[4]; uint2 u2; unsigned u[2]; };

// ws layout
#define WFRAG_OFF 0u
#define WFRAG_BYTES (128u*5u*32u*64u*8u*2u)          // 20971520
#define WHT_OFF   (WFRAG_OFF + WFRAG_BYTES)          // 20971520
#define WHT_BYTES (2048u*1024u*2u)                   // 4194304
#define S16A_OFF  (WHT_OFF + WHT_BYTES)              // 25165824
#define S16_BYTES (NB*NH*2u)                         // 131072
#define S16B_OFF  (S16A_OFF + S16_BYTES)
#define FLAG_OFF  (S16B_OFF + S16_BYTES)             // 128 flags, 32 B apart = 4 KB

// --------------------------------------------------------------------------
// Prep 0: recurrent weights -> fp16 A-operand fragments.
// frag id = ((wg*5+l)*32+ks)*64+lane; lane: m = lane&15 (m>=8 -> t-gate),
// q = lane>>4; element j: W[gate][g = wg*8 + (m&7)][k = ks*32 + q*8 + j].
__global__ __launch_bounds__(256) void prep_wfrag(
    const float* __restrict__ rh_w, const float* __restrict__ rt_w,
    _Float16* __restrict__ wfrag)
{
  int id = blockIdx.x * 256 + threadIdx.x;   // 0 .. 128*5*32*64
  int lane = id & 63;
  int ks = (id >> 6) & 31;
  int wl = id >> 11;            // wg*5 + l
  int l = wl % 5;
  int wg = wl / 5;
  int m = lane & 15, q = lane >> 4;
  int gate = m >> 3;
  int g = wg * 8 + (m & 7);
  int k0 = ks * 32 + q * 8;
  const float* src = (gate ? rt_w : rh_w) + ((size_t)l * NH + g) * NH + k0;
  float4 f0 = ((const float4*)src)[0];
  float4 f1 = ((const float4*)src)[1];
  HV8 t;
  t.h[0] = (_Float16)f0.x; t.h[1] = (_Float16)f0.y;
  t.h[2] = (_Float16)f0.z; t.h[3] = (_Float16)f0.w;
  t.h[4] = (_Float16)f1.x; t.h[5] = (_Float16)f1.y;
  t.h[6] = (_Float16)f1.z; t.h[7] = (_Float16)f1.w;
  *(uint4*)(wfrag + (size_t)id * 8) = t.u;
}

// --------------------------------------------------------------------------
// Prep 1: w_h/w_t [IN][H] fp32 -> whT [2048][1024] fp16. Also init s16a and
// the per-WG stage flags.
__global__ __launch_bounds__(256) void prep_misc(
    const float* __restrict__ w_h, const float* __restrict__ w_t,
    const float* __restrict__ s_in,
    _Float16* __restrict__ whT, _Float16* __restrict__ s16a,
    unsigned* __restrict__ flags)
{
  int id = blockIdx.x * 256 + threadIdx.x;   // 0 .. 128*2048
  int nn = id & 2047;
  int kc = id >> 11;                          // 0..127
  int gate = nn >> 10, g = nn & 1023;
  const float* src = gate ? w_t : w_h;
  HV8 t;
#pragma unroll
  for (int j = 0; j < 8; j++) t.h[j] = (_Float16)src[(size_t)(kc * 8 + j) * NH + g];
  *(uint4*)(whT + (size_t)nn * NIN + kc * 8) = t.u;
  if (id < NB * NH) s16a[id] = (_Float16)s_in[id];
  if (id < NWG) flags[id * 8] = 0u;
}

// --------------------------------------------------------------------------
// Phase 1: WHX/WTX = x @ [w_h | w_t]  (M=32768, N=2048, K=1024), fp16 MFMA.
// Output packed fp16: outH[row*2048 + gate*1024 + g], row = b*T + t.
__global__ __launch_bounds__(256) void gemm_in(
    const float* __restrict__ x, const _Float16* __restrict__ whT,
    _Float16* outH)
{
  __shared__ __align__(16) _Float16 aS[8][64][8];
  __shared__ __align__(16) _Float16 bS[8][64][8];
  int tid = threadIdx.x, lane = tid & 63, w = tid >> 6;
  int m0 = blockIdx.x * 128, n0 = blockIdx.y * 128;
  int srow = tid >> 1, shf = tid & 1;
  int q = lane >> 4, nl = lane & 15;
  floatx4 acc[4][4] = {};
  const float*    ap = x   + (size_t)(m0 + srow) * NIN + shf * 16;
  const _Float16* bp = whT + (size_t)(n0 + srow) * NIN + shf * 16;
  int la = ((shf * 2)     << 4) | (srow & 15);
  int lb = ((shf * 2 + 1) << 4) | (srow & 15);
  int smt = srow >> 4;
  for (int kc = 0; kc < 32; kc++) {
    float4 f0 = ((const float4*)ap)[0];
    float4 f1 = ((const float4*)ap)[1];
    float4 f2 = ((const float4*)ap)[2];
    float4 f3 = ((const float4*)ap)[3];
    HV8 ua, ub;
    ua.h[0]=(_Float16)f0.x; ua.h[1]=(_Float16)f0.y; ua.h[2]=(_Float16)f0.z; ua.h[3]=(_Float16)f0.w;
    ua.h[4]=(_Float16)f1.x; ua.h[5]=(_Float16)f1.y; ua.h[6]=(_Float16)f1.z; ua.h[7]=(_Float16)f1.w;
    ub.h[0]=(_Float16)f2.x; ub.h[1]=(_Float16)f2.y; ub.h[2]=(_Float16)f2.z; ub.h[3]=(_Float16)f2.w;
    ub.h[4]=(_Float16)f3.x; ub.h[5]=(_Float16)f3.y; ub.h[6]=(_Float16)f3.z; ub.h[7]=(_Float16)f3.w;
    uint4 b0 = ((const uint4*)bp)[0];
    uint4 b1 = ((const uint4*)bp)[1];
    *(uint4*)&aS[smt][la][0] = ua.u;
    *(uint4*)&aS[smt][lb][0] = ub.u;
    *(uint4*)&bS[smt][la][0] = b0;
    *(uint4*)&bS[smt][lb][0] = b1;
    __syncthreads();
    half8 af[4], bf[4];
#pragma unroll
    for (int mt = 0; mt < 4; mt++) af[mt] = *(const half8*)&aS[(w >> 1) * 4 + mt][lane][0];
#pragma unroll
    for (int nt = 0; nt < 4; nt++) bf[nt] = *(const half8*)&bS[(w & 1) * 4 + nt][lane][0];
#pragma unroll
    for (int mt = 0; mt < 4; mt++)
#pragma unroll
      for (int nt = 0; nt < 4; nt++)
        acc[mt][nt] = __builtin_amdgcn_mfma_f32_16x16x32_f16(af[mt], bf[nt], acc[mt][nt], 0, 0, 0);
    __syncthreads();
    ap += 32; bp += 32;
  }
#pragma unroll
  for (int mt = 0; mt < 4; mt++)
#pragma unroll
    for (int nt = 0; nt < 4; nt++) {
      int nG = n0 + (w & 1) * 64 + nt * 16 + nl;
      int gate = nG >> 10, g = nG & 1023;
#pragma unroll
      for (int i = 0; i < 4; i++) {
        int row = m0 + (w >> 1) * 64 + mt * 16 + q * 4 + i;
        outH[(size_t)row * 2048 + gate * 1024 + g] = (_Float16)acc[mt][nt][i];
      }
    }
}

// --------------------------------------------------------------------------
// sc1-bypass async s loads: issued via asm, consumed after counted vmcnt.
#define LD1(dst, base, OFF) \
  asm volatile("global_load_dwordx4 %0, %1, off offset:" OFF " sc0 sc1" \
               : "=v"(dst) : "v"(base) : "memory")
#define ISSUE4(Bf, OFF) do { \
  LD1(Bf##0, ap0, OFF); LD1(Bf##1, ap1, OFF); \
  LD1(Bf##2, ap2, OFF); LD1(Bf##3, ap3, OFF); } while (0)
#define WAITV(N) do { \
  asm volatile("s_waitcnt vmcnt(" #N ")" ::: "memory"); \
  __builtin_amdgcn_sched_barrier(0); } while (0)
#define MFMA4(Bf, KS) do { \
  acc0 = __builtin_amdgcn_mfma_f32_16x16x32_f16(Wl[KS], __builtin_bit_cast(half8, Bf##0), acc0, 0, 0, 0); \
  acc1 = __builtin_amdgcn_mfma_f32_16x16x32_f16(Wl[KS], __builtin_bit_cast(half8, Bf##1), acc1, 0, 0, 0); \
  acc2 = __builtin_amdgcn_mfma_f32_16x16x32_f16(Wl[KS], __builtin_bit_cast(half8, Bf##2), acc2, 0, 0, 0); \
  acc3 = __builtin_amdgcn_mfma_f32_16x16x32_f16(Wl[KS], __builtin_bit_cast(half8, Bf##3), acc3, 0, 0, 0); } while (0)

// --------------------------------------------------------------------------
// Persistent recurrence. 128 WGs x 256 threads, all co-resident.
// Decentralized sync: per-WG monotonic stage flag (plain sc1 store, no RMW).
// Wave w consumes s rows h in [w*256, w*256+256), produced by WGs
// [w*32, w*32+32) -> each wave waits ONLY on those 32 flags. Writes of step j
// are safe (2 buffers) because they follow the __syncthreads after all 4
// waves' waits: union of producer sets = all 128 WGs at flag >= j, and
// flag >= j implies that WG's step j-1 reads were consumed before its stores.
// s reads bypass L1/L2 (sc0 sc1) -> no acquire fence / L2 flash-inv needed.
__global__ __launch_bounds__(256, 1) void rhn_rec(
    const _Float16* __restrict__ wfrag,
    _Float16* s16a, _Float16* s16b,
    const float* __restrict__ s_in,
    const float* __restrict__ rh_b, const float* __restrict__ rt_b,
    float* out, unsigned* flags)
{
  __shared__ floatx4 red[4][4][64];
  int wg = blockIdx.x;
  int tid = threadIdx.x, lane = tid & 63, w = tid >> 6;
  int n = lane & 15, q = lane >> 4;
  int gate = q >> 1;                  // epilogue: which gate this lane's rows are
  int g0 = wg * 8 + (q & 1) * 4;      // epilogue: 4 consecutive g columns
  int b = w * 16 + n;                 // epilogue: this lane's batch row
  _Float16* outH = (_Float16*)out;

  // register-resident weight fragments: 5 layers x 8 local ksteps
  half8 W[5][8];
#pragma unroll
  for (int l = 0; l < 5; l++)
#pragma unroll
    for (int ks = 0; ks < 8; ks++)
      W[l][ks] = *(const half8*)(wfrag +
          ((((size_t)wg * 5 + l) * 32 + (w * 8 + ks)) * 64 + lane) * 8);

  float bias4[5][4];
#pragma unroll
  for (int l = 0; l < 5; l++)
#pragma unroll
    for (int i = 0; i < 4; i++)
      bias4[l][i] = (gate ? rt_b : rh_b)[l * NH + g0 + i];

  float sold[4];
#pragma unroll
  for (int i = 0; i < 4; i++)
    sold[i] = s_in[(size_t)b * NH + g0 + i];

  const _Float16* sRead = s16a;
  _Float16* sWrite = s16b;
  unsigned stage = 0;
  // this wave's producer flag (32 producers, 2 lanes per flag)
  const unsigned* fp = flags + (size_t)(w * 32 + (lane & 31)) * 8;

#pragma unroll 1
  for (int t = 0; t < NT; t++) {
#pragma unroll
    for (int l = 0; l < 5; l++) {
      // 1. per-wave wait: only this wave's K-slice producers
      while (__hip_atomic_load(fp, __ATOMIC_RELAXED, __HIP_MEMORY_SCOPE_AGENT) < stage) {}
      __builtin_amdgcn_sched_barrier(0);

      // 2. issue wx load now (l==0), convert AFTER the MFMA pipe (hides LLC miss)
      HV4 wx;
      if (l == 0)
        wx.u2 = *(const uint2*)(outH + ((size_t)b * NT + t) * 2048 + gate * 1024 + g0);

      // 3. s-fragment pipeline: sc1 loads, double-buffered groups of 4
      const _Float16* ap0 = sRead + (size_t)n * NH + w * 256 + q * 8;
      const _Float16* ap1 = ap0 + 16 * NH;
      const _Float16* ap2 = ap0 + 32 * NH;
      const _Float16* ap3 = ap0 + 48 * NH;
      const half8* Wl = W[l];
      floatx4 acc0 = {}, acc1 = {}, acc2 = {}, acc3 = {};
      uint4 bufA0, bufA1, bufA2, bufA3, bufB0, bufB1, bufB2, bufB3;
      ISSUE4(bufA, "0");
      ISSUE4(bufB, "64");
      WAITV(4); MFMA4(bufA, 0);
      ISSUE4(bufA, "128");
      WAITV(4); MFMA4(bufB, 1);
      ISSUE4(bufB, "192");
      WAITV(4); MFMA4(bufA, 2);
      ISSUE4(bufA, "256");
      WAITV(4); MFMA4(bufB, 3);
      ISSUE4(bufB, "320");
      WAITV(4); MFMA4(bufA, 4);
      ISSUE4(bufA, "384");
      WAITV(4); MFMA4(bufB, 5);
      ISSUE4(bufB, "448");
      WAITV(4); MFMA4(bufA, 6);
      WAITV(0); MFMA4(bufB, 7);

      // 4. cross-wave K reduction; wave w takes batch-tile w
      red[w][0][lane] = acc0; red[w][1][lane] = acc1;
      red[w][2][lane] = acc2; red[w][3][lane] = acc3;
      __syncthreads();
      floatx4 pre = red[0][w][lane] + red[1][w][lane] + red[2][w][lane] + red[3][w][lane];

      // 5. activations: tanh(x) = 2*sigmoid(2x)-1
      float act[4];
#pragma unroll
      for (int i = 0; i < 4; i++) {
        float xv = pre[i] + bias4[l][i];
        if (l == 0) xv += (float)wx.h[i];
        float y = gate ? xv : 2.f * xv;
        float sg = 1.f / (1.f + __expf(-y));
        act[i] = gate ? sg : (2.f * sg - 1.f);
      }
      // highway blend: h-lanes (q<2) fetch partner sigmoid from lane+32
      float sn[4];
#pragma unroll
      for (int i = 0; i < 4; i++) {
        float tp = __shfl(act[i], lane ^ 32, 64);
        sn[i] = (act[i] - sold[i]) * tp + sold[i];
      }
      if (q < 2) {
#pragma unroll
        for (int i = 0; i < 4; i++) sold[i] = sn[i];
        HV4 pk;
#pragma unroll
        for (int i = 0; i < 4; i++) pk.h[i] = (_Float16)sold[i];
        unsigned* dstu = (unsigned*)(sWrite + (size_t)b * NH + g0);
        __hip_atomic_store(dstu, pk.u[0], __ATOMIC_RELAXED, __HIP_MEMORY_SCOPE_AGENT);
        __hip_atomic_store(dstu + 1, pk.u[1], __ATOMIC_RELAXED, __HIP_MEMORY_SCOPE_AGENT);
        if (l == 4) {
          float4 o;
          o.x = sold[0]; o.y = sold[1]; o.z = sold[2]; o.w = sold[3];
          *(float4*)(out + ((size_t)b * NT + t) * NH + g0) = o;
          if (t == NT - 1)
            *(float4*)(out + (size_t)NB * NT * NH + (size_t)b * NH + g0) = o;
        }
      }
      // swap ping-pong state buffers
      {
        const _Float16* tr = sRead;
        sRead = sWrite;
        sWrite = (_Float16*)tr;
      }
      // 6. publish: drain this wave's LLC stores, converge WG, bump flag
      asm volatile("s_waitcnt vmcnt(0)" ::: "memory");
      __syncthreads();
      stage++;
      if (tid == 0)
        __hip_atomic_store(flags + (size_t)wg * 8, stage,
                           __ATOMIC_RELAXED, __HIP_MEMORY_SCOPE_AGENT);
    }
  }
}

// --------------------------------------------------------------------------
extern "C" void kernel_launch(void* const* d_in, const int* in_sizes, int n_in,
                              void* d_out, int out_size, void* d_ws, size_t ws_size,
                              hipStream_t stream)
{
  (void)in_sizes; (void)n_in; (void)out_size; (void)ws_size;
  const float* x    = (const float*)d_in[0];
  const float* s_in = (const float*)d_in[1];
  const float* w_h  = (const float*)d_in[2];
  const float* w_t  = (const float*)d_in[3];
  const float* rh_w = (const float*)d_in[4];
  const float* rh_b = (const float*)d_in[5];
  const float* rt_w = (const float*)d_in[6];
  const float* rt_b = (const float*)d_in[7];
  float* out = (float*)d_out;
  char* ws = (char*)d_ws;
  _Float16* wfrag = (_Float16*)(ws + WFRAG_OFF);
  _Float16* whT   = (_Float16*)(ws + WHT_OFF);
  _Float16* s16a  = (_Float16*)(ws + S16A_OFF);
  _Float16* s16b  = (_Float16*)(ws + S16B_OFF);
  unsigned* flags = (unsigned*)(ws + FLAG_OFF);

  hipLaunchKernelGGL(prep_wfrag, dim3(5120), dim3(256), 0, stream, rh_w, rt_w, wfrag);
  hipLaunchKernelGGL(prep_misc,  dim3(1024), dim3(256), 0, stream, w_h, w_t, s_in, whT, s16a, flags);
  hipLaunchKernelGGL(gemm_in,    dim3(256, 16), dim3(256), 0, stream, x, whT, (_Float16*)out);
  hipLaunchKernelGGL(rhn_rec,    dim3(NWG), dim3(256), 0, stream, wfrag, s16a, s16b, s_in, rh_b, rt_b, out, flags);
}

// Round 2
// 10033.714 us; speedup vs baseline: 2.5644x; 1.6396x over previous
//
#include <hip/hip_runtime.h>

#define NB 64
#define NT 512
#define NIN 1024
#define NH 1024
#define NWG 128

typedef _Float16 half8 __attribute__((ext_vector_type(8)));
typedef float floatx4 __attribute__((ext_vector_type(4)));

union HV8 { _Float16 h[8]; uint4 u; };
union HV4 { _Float16 h[4]; uint2 u2; unsigned u[2]; };

// ws layout
#define WFRAG_OFF 0u
#define WFRAG_BYTES (32u*5u*4u*32u*64u*8u*2u)        // 20971520
#define WHT_OFF   (WFRAG_OFF + WFRAG_BYTES)          // 20971520
#define WHT_BYTES (2048u*1024u*2u)                   // 4194304
#define S16A_OFF  (WHT_OFF + WHT_BYTES)              // 25165824
#define S16_BYTES (NB*NH*2u)                         // 131072
#define S16B_OFF  (S16A_OFF + S16_BYTES)
#define FLAG_OFF  (S16B_OFF + S16_BYTES)             // 128 flags, 32 B apart

// --------------------------------------------------------------------------
// Prep 0: recurrent weights -> fp16 A-operand fragments, 2D-decomposition
// layout. frag f = (((c*5+l)*4+mt)*32+ks)*64+lane; lane: m=lane&15
// (m>=8 -> t-gate), q=lane>>4; element j:
// W[gate][g = c*32 + mt*8 + (m&7)][k = ks*32 + q*8 + j].
__global__ __launch_bounds__(256) void prep_wfrag(
    const float* __restrict__ rh_w, const float* __restrict__ rt_w,
    _Float16* __restrict__ wfrag)
{
  int id = blockIdx.x * 256 + threadIdx.x;   // 0 .. 32*5*4*32*64
  int lane = id & 63;
  int r = id >> 6;
  int ks = r & 31; r >>= 5;
  int mt = r & 3;  r >>= 2;
  int l = r % 5;
  int c = r / 5;
  int m = lane & 15, q = lane >> 4;
  int gate = m >> 3;
  int g = c * 32 + mt * 8 + (m & 7);
  int k0 = ks * 32 + q * 8;
  const float* src = (gate ? rt_w : rh_w) + ((size_t)l * NH + g) * NH + k0;
  float4 f0 = ((const float4*)src)[0];
  float4 f1 = ((const float4*)src)[1];
  HV8 t;
  t.h[0] = (_Float16)f0.x; t.h[1] = (_Float16)f0.y;
  t.h[2] = (_Float16)f0.z; t.h[3] = (_Float16)f0.w;
  t.h[4] = (_Float16)f1.x; t.h[5] = (_Float16)f1.y;
  t.h[6] = (_Float16)f1.z; t.h[7] = (_Float16)f1.w;
  *(uint4*)(wfrag + (size_t)id * 8) = t.u;
}

// --------------------------------------------------------------------------
// Prep 1: w_h/w_t [IN][H] fp32 -> whT [2048][1024] fp16. Also init s16a and
// the per-WG stage flags.
__global__ __launch_bounds__(256) void prep_misc(
    const float* __restrict__ w_h, const float* __restrict__ w_t,
    const float* __restrict__ s_in,
    _Float16* __restrict__ whT, _Float16* __restrict__ s16a,
    unsigned* __restrict__ flags)
{
  int id = blockIdx.x * 256 + threadIdx.x;   // 0 .. 128*2048
  int nn = id & 2047;
  int kc = id >> 11;                          // 0..127
  int gate = nn >> 10, g = nn & 1023;
  const float* src = gate ? w_t : w_h;
  HV8 t;
#pragma unroll
  for (int j = 0; j < 8; j++) t.h[j] = (_Float16)src[(size_t)(kc * 8 + j) * NH + g];
  *(uint4*)(whT + (size_t)nn * NIN + kc * 8) = t.u;
  if (id < NB * NH) s16a[id] = (_Float16)s_in[id];
  if (id < NWG) flags[id * 8] = 0u;
}

// --------------------------------------------------------------------------
// Phase 1: WHX/WTX = x @ [w_h | w_t]  (M=32768, N=2048, K=1024), fp16 MFMA.
// Output packed fp16: outH[row*2048 + gate*1024 + g], row = b*T + t.
__global__ __launch_bounds__(256) void gemm_in(
    const float* __restrict__ x, const _Float16* __restrict__ whT,
    _Float16* outH)
{
  __shared__ __align__(16) _Float16 aS[8][64][8];
  __shared__ __align__(16) _Float16 bS[8][64][8];
  int tid = threadIdx.x, lane = tid & 63, w = tid >> 6;
  int m0 = blockIdx.x * 128, n0 = blockIdx.y * 128;
  int srow = tid >> 1, shf = tid & 1;
  int q = lane >> 4, nl = lane & 15;
  floatx4 acc[4][4] = {};
  const float*    ap = x   + (size_t)(m0 + srow) * NIN + shf * 16;
  const _Float16* bp = whT + (size_t)(n0 + srow) * NIN + shf * 16;
  int la = ((shf * 2)     << 4) | (srow & 15);
  int lb = ((shf * 2 + 1) << 4) | (srow & 15);
  int smt = srow >> 4;
  for (int kc = 0; kc < 32; kc++) {
    float4 f0 = ((const float4*)ap)[0];
    float4 f1 = ((const float4*)ap)[1];
    float4 f2 = ((const float4*)ap)[2];
    float4 f3 = ((const float4*)ap)[3];
    HV8 ua, ub;
    ua.h[0]=(_Float16)f0.x; ua.h[1]=(_Float16)f0.y; ua.h[2]=(_Float16)f0.z; ua.h[3]=(_Float16)f0.w;
    ua.h[4]=(_Float16)f1.x; ua.h[5]=(_Float16)f1.y; ua.h[6]=(_Float16)f1.z; ua.h[7]=(_Float16)f1.w;
    ub.h[0]=(_Float16)f2.x; ub.h[1]=(_Float16)f2.y; ub.h[2]=(_Float16)f2.z; ub.h[3]=(_Float16)f2.w;
    ub.h[4]=(_Float16)f3.x; ub.h[5]=(_Float16)f3.y; ub.h[6]=(_Float16)f3.z; ub.h[7]=(_Float16)f3.w;
    uint4 b0 = ((const uint4*)bp)[0];
    uint4 b1 = ((const uint4*)bp)[1];
    *(uint4*)&aS[smt][la][0] = ua.u;
    *(uint4*)&aS[smt][lb][0] = ub.u;
    *(uint4*)&bS[smt][la][0] = b0;
    *(uint4*)&bS[smt][lb][0] = b1;
    __syncthreads();
    half8 af[4], bf[4];
#pragma unroll
    for (int mt = 0; mt < 4; mt++) af[mt] = *(const half8*)&aS[(w >> 1) * 4 + mt][lane][0];
#pragma unroll
    for (int nt = 0; nt < 4; nt++) bf[nt] = *(const half8*)&bS[(w & 1) * 4 + nt][lane][0];
#pragma unroll
    for (int mt = 0; mt < 4; mt++)
#pragma unroll
      for (int nt = 0; nt < 4; nt++)
        acc[mt][nt] = __builtin_amdgcn_mfma_f32_16x16x32_f16(af[mt], bf[nt], acc[mt][nt], 0, 0, 0);
    __syncthreads();
    ap += 32; bp += 32;
  }
#pragma unroll
  for (int mt = 0; mt < 4; mt++)
#pragma unroll
    for (int nt = 0; nt < 4; nt++) {
      int nG = n0 + (w & 1) * 64 + nt * 16 + nl;
      int gate = nG >> 10, g = nG & 1023;
#pragma unroll
      for (int i = 0; i < 4; i++) {
        int row = m0 + (w >> 1) * 64 + mt * 16 + q * 4 + i;
        outH[(size_t)row * 2048 + gate * 1024 + g] = (_Float16)acc[mt][nt][i];
      }
    }
}

// --------------------------------------------------------------------------
// asm load macros. LDG = normal cached (W from L2); LDS_SC = L1/L2 bypass
// (s, always LLC-fresh). WAITV = counted drain + sched fence (rule #18).
#define LDG(dst, base, OFF) \
  asm volatile("global_load_dwordx4 %0, %1, off offset:" OFF \
               : "=v"(dst) : "v"(base) : "memory")
#define LDS_SC(dst, base, OFF) \
  asm volatile("global_load_dwordx4 %0, %1, off offset:" OFF " sc0 sc1" \
               : "=v"(dst) : "v"(base) : "memory")
#define WAITV(N) do { \
  asm volatile("s_waitcnt vmcnt(" #N ")" ::: "memory"); \
  __builtin_amdgcn_sched_barrier(0); } while (0)
#define ISS4(S, P0, P1, P2, P3, OFF) do { \
  LDG(wv##S##0, P0, OFF); LDG(wv##S##1, P1, OFF); \
  LDG(wv##S##2, P2, OFF); LDG(wv##S##3, P3, OFF); } while (0)
#define MFMA4(W0_, W1_, W2_, W3_, S_) do { \
  half8 bb_ = __builtin_bit_cast(half8, S_); \
  acc0 = __builtin_amdgcn_mfma_f32_16x16x32_f16(__builtin_bit_cast(half8, W0_), bb_, acc0, 0, 0, 0); \
  acc1 = __builtin_amdgcn_mfma_f32_16x16x32_f16(__builtin_bit_cast(half8, W1_), bb_, acc1, 0, 0, 0); \
  acc2 = __builtin_amdgcn_mfma_f32_16x16x32_f16(__builtin_bit_cast(half8, W2_), bb_, acc2, 0, 0, 0); \
  acc3 = __builtin_amdgcn_mfma_f32_16x16x32_f16(__builtin_bit_cast(half8, W3_), bb_, acc3, 0, 0, 0); } while (0)

// --------------------------------------------------------------------------
// Persistent recurrence, 2D decomposition: 4 independent groups (16 batches
// each) x 32 column-slice WGs (32 g-cols x 2 gates each = 4 M-tiles).
// Block decode puts the 4 WGs sharing a column-slice on one XCD (b%8 pattern)
// so the per-XCD W working set (4 slices x 640 KB = 2.6 MB) is L2-resident.
// Per layer: W prefetch (L2, flag-independent) issues BEFORE the flag wait;
// s loads (LLC, sc0sc1) double-buffered behind it with counted vmcnt.
// Wave w consumes s k-slice [w*256,(w+1)*256) = producers c in [w*8,w*8+8)
// of its own group -> waits on 8 flags; union over 4 waves = all 32 group
// producers, so 2-buffer ping-pong stays safe (stores after __syncthreads).
__global__ __launch_bounds__(256, 1) void rhn_rec(
    const _Float16* __restrict__ wfrag,
    _Float16* s16a, _Float16* s16b,
    const float* __restrict__ s_in,
    const float* __restrict__ rh_b, const float* __restrict__ rt_b,
    float* out, unsigned* flags)
{
  __shared__ floatx4 red[4][4][64];
  int bIdx = blockIdx.x;
  int inner = bIdx >> 3;
  int grp = inner & 3;                       // batch group 0..3
  int c = (bIdx & 7) + 8 * (inner >> 2);     // column slice 0..31
  int tid = threadIdx.x, lane = tid & 63, w = tid >> 6;
  int n = lane & 15, q = lane >> 4;
  int gate = q >> 1;                         // epilogue gate for this lane
  int c0 = c * 32 + w * 8 + (q & 1) * 4;     // 4 consecutive g columns
  int bg = grp * 16 + n;                     // global batch row
  _Float16* outH = (_Float16*)out;

  float bias4[5][4];
#pragma unroll
  for (int l = 0; l < 5; l++)
#pragma unroll
    for (int i = 0; i < 4; i++)
      bias4[l][i] = (gate ? rt_b : rh_b)[l * NH + c0 + i];

  float sold[4];
#pragma unroll
  for (int i = 0; i < 4; i++)
    sold[i] = s_in[(size_t)bg * NH + c0 + i];

  const _Float16* sRead = s16a;
  _Float16* sWrite = s16b;
  unsigned stage = 0;
  // this wave's 8 producer flags (8 lanes per flag)
  const unsigned* fp = flags + (size_t)(grp * 32 + w * 8 + (lane & 7)) * 8;
  // W fragment base for this (c, wave, lane); per-layer/mt/ks offsets added
  const char* wbase0 = (const char*)wfrag +
      (size_t)c * 655360u + (unsigned)(w * 8192 + lane * 16);

#pragma unroll 1
  for (int t = 0; t < NT; t++) {
#pragma unroll
    for (int l = 0; l < 5; l++) {
      // wx for layer 0: load + convert BEFORE the asm region (keeps vmcnt
      // counting clean; overlaps the flag wait)
      float wxv[4] = {0.f, 0.f, 0.f, 0.f};
      if (l == 0) {
        HV4 wx;
        wx.u2 = *(const uint2*)(outH + ((size_t)bg * NT + t) * 2048 + gate * 1024 + c0);
#pragma unroll
        for (int i = 0; i < 4; i++) wxv[i] = (float)wx.h[i];
      }
      const char* wbL = wbase0 + (size_t)l * 131072u;
      const char* wp0 = wbL;
      const char* wp1 = wbL + 32768;
      const char* wp2 = wbL + 65536;
      const char* wp3 = wbL + 98304;
      const char* xp0 = wbL + 4096;
      const char* xp1 = wbL + 36864;
      const char* xp2 = wbL + 69632;
      const char* xp3 = wbL + 102400;
      const char* sp = (const char*)sRead +
          (size_t)bg * 2048u + (unsigned)(w * 512 + q * 16);

      uint4 wv00, wv01, wv02, wv03, wv10, wv11, wv12, wv13;
      uint4 wv20, wv21, wv22, wv23, wv30, wv31, wv32, wv33;
      uint4 sv0, sv1, sv2, sv3;
      floatx4 acc0 = {}, acc1 = {}, acc2 = {}, acc3 = {};

      // W prologue: ksteps 0..2 (L2 latency hides under the flag wait)
      ISS4(0, wp0, wp1, wp2, wp3, "0");
      ISS4(1, wp0, wp1, wp2, wp3, "1024");
      ISS4(2, wp0, wp1, wp2, wp3, "2048");

      // flag wait: only this wave's 8 K-slice producers
      while (__hip_atomic_load(fp, __ATOMIC_RELAXED, __HIP_MEMORY_SCOPE_AGENT) < stage) {}
      __builtin_amdgcn_sched_barrier(0);

      // s prologue + pipelined loop (vmcnt table verified for both
      // drained-poll and undrained-poll FIFO scenarios)
      LDS_SC(sv0, sp, "0");
      LDS_SC(sv1, sp, "64");
      LDS_SC(sv2, sp, "128");
      ISS4(3, wp0, wp1, wp2, wp3, "3072");
      LDS_SC(sv3, sp, "192");
      WAITV(7);  MFMA4(wv00, wv01, wv02, wv03, sv0);
      ISS4(0, xp0, xp1, xp2, xp3, "0");
      LDS_SC(sv0, sp, "256");
      WAITV(11); MFMA4(wv10, wv11, wv12, wv13, sv1);
      ISS4(1, xp0, xp1, xp2, xp3, "1024");
      LDS_SC(sv1, sp, "320");
      WAITV(15); MFMA4(wv20, wv21, wv22, wv23, sv2);
      ISS4(2, xp0, xp1, xp2, xp3, "2048");
      LDS_SC(sv2, sp, "384");
      WAITV(15); MFMA4(wv30, wv31, wv32, wv33, sv3);
      ISS4(3, xp0, xp1, xp2, xp3, "3072");
      LDS_SC(sv3, sp, "448");
      WAITV(15); MFMA4(wv00, wv01, wv02, wv03, sv0);
      WAITV(10); MFMA4(wv10, wv11, wv12, wv13, sv1);
      WAITV(5);  MFMA4(wv20, wv21, wv22, wv23, sv2);
      WAITV(0);  MFMA4(wv30, wv31, wv32, wv33, sv3);

      // cross-wave K reduction; wave w takes M-tile w
      red[w][0][lane] = acc0; red[w][1][lane] = acc1;
      red[w][2][lane] = acc2; red[w][3][lane] = acc3;
      __syncthreads();
      floatx4 pre = red[0][w][lane] + red[1][w][lane] + red[2][w][lane] + red[3][w][lane];

      // activations: tanh(x) = 2*sigmoid(2x)-1
      float act[4];
#pragma unroll
      for (int i = 0; i < 4; i++) {
        float xv = pre[i] + bias4[l][i] + wxv[i];
        float y = gate ? xv : 2.f * xv;
        float sg = 1.f / (1.f + __expf(-y));
        act[i] = gate ? sg : (2.f * sg - 1.f);
      }
      // highway blend: h-lanes (q<2) fetch partner sigmoid from lane+32
      float sn[4];
#pragma unroll
      for (int i = 0; i < 4; i++) {
        float tp = __shfl(act[i], lane ^ 32, 64);
        sn[i] = (act[i] - sold[i]) * tp + sold[i];
      }
      if (q < 2) {
#pragma unroll
        for (int i = 0; i < 4; i++) sold[i] = sn[i];
        HV4 pk;
#pragma unroll
        for (int i = 0; i < 4; i++) pk.h[i] = (_Float16)sold[i];
        unsigned* dstu = (unsigned*)(sWrite + (size_t)bg * NH + c0);
        __hip_atomic_store(dstu, pk.u[0], __ATOMIC_RELAXED, __HIP_MEMORY_SCOPE_AGENT);
        __hip_atomic_store(dstu + 1, pk.u[1], __ATOMIC_RELAXED, __HIP_MEMORY_SCOPE_AGENT);
        if (l == 4) {
          float4 o;
          o.x = sold[0]; o.y = sold[1]; o.z = sold[2]; o.w = sold[3];
          *(float4*)(out + ((size_t)bg * NT + t) * NH + c0) = o;
          if (t == NT - 1)
            *(float4*)(out + (size_t)NB * NT * NH + (size_t)bg * NH + c0) = o;
        }
      }
      // swap ping-pong state buffers
      {
        const _Float16* tr = sRead;
        sRead = sWrite;
        sWrite = (_Float16*)tr;
      }
      // publish: drain LLC stores, converge WG, bump this WG's flag
      asm volatile("s_waitcnt vmcnt(0)" ::: "memory");
      __syncthreads();
      stage++;
      if (tid == 0)
        __hip_atomic_store(flags + (size_t)(grp * 32 + c) * 8, stage,
                           __ATOMIC_RELAXED, __HIP_MEMORY_SCOPE_AGENT);
    }
  }
}

// --------------------------------------------------------------------------
extern "C" void kernel_launch(void* const* d_in, const int* in_sizes, int n_in,
                              void* d_out, int out_size, void* d_ws, size_t ws_size,
                              hipStream_t stream)
{
  (void)in_sizes; (void)n_in; (void)out_size; (void)ws_size;
  const float* x    = (const float*)d_in[0];
  const float* s_in = (const float*)d_in[1];
  const float* w_h  = (const float*)d_in[2];
  const float* w_t  = (const float*)d_in[3];
  const float* rh_w = (const float*)d_in[4];
  const float* rh_b = (const float*)d_in[5];
  const float* rt_w = (const float*)d_in[6];
  const float* rt_b = (const float*)d_in[7];
  float* out = (float*)d_out;
  char* ws = (char*)d_ws;
  _Float16* wfrag = (_Float16*)(ws + WFRAG_OFF);
  _Float16* whT   = (_Float16*)(ws + WHT_OFF);
  _Float16* s16a  = (_Float16*)(ws + S16A_OFF);
  _Float16* s16b  = (_Float16*)(ws + S16B_OFF);
  unsigned* flags = (unsigned*)(ws + FLAG_OFF);

  hipLaunchKernelGGL(prep_wfrag, dim3(5120), dim3(256), 0, stream, rh_w, rt_w, wfrag);
  hipLaunchKernelGGL(prep_misc,  dim3(1024), dim3(256), 0, stream, w_h, w_t, s_in, whT, s16a, flags);
  hipLaunchKernelGGL(gemm_in,    dim3(256, 16), dim3(256), 0, stream, x, whT, (_Float16*)out);
  hipLaunchKernelGGL(rhn_rec,    dim3(NWG), dim3(256), 0, stream, wfrag, s16a, s16b, s_in, rh_b, rt_b, out, flags);
}